// Round 8
// baseline (276.571 us; speedup 1.0000x reference)
//
#include <hip/hip_runtime.h>

#define N_NODES 16384
#define N_EDGES 32768
#define D 128
#define EDGE_DIM 10
#define KH 32          // edge-hidden dim
#define BM 128         // edges per msg block
#define XST 136        // padded LDS row stride (f16)
#define NBL 32         // nodes per node_update block

typedef _Float16 f16;
typedef _Float16 f16x4 __attribute__((ext_vector_type(4)));
typedef _Float16 f16x8 __attribute__((ext_vector_type(8)));
typedef float f32x4 __attribute__((ext_vector_type(4)));

// ---- CSR build ----
__global__ __launch_bounds__(256) void deg_count_kernel(
    const int* __restrict__ ei, int* __restrict__ deg) {
  int e = blockIdx.x * blockDim.x + threadIdx.x;
  if (e < N_EDGES) atomicAdd(&deg[ei[N_EDGES + e]], 1);
}

__global__ __launch_bounds__(1024) void scan_kernel(
    const int* __restrict__ deg, int* __restrict__ rs, int* __restrict__ fill) {
  __shared__ int part[1024];
  int t = threadIdx.x;
  int base = t * 16;
  int loc[16], s = 0;
#pragma unroll
  for (int j = 0; j < 16; j++) { loc[j] = deg[base + j]; s += loc[j]; }
  part[t] = s;
  __syncthreads();
  for (int off = 1; off < 1024; off <<= 1) {
    int add = (t >= off) ? part[t - off] : 0;
    __syncthreads();
    part[t] += add;
    __syncthreads();
  }
  int run = t ? part[t - 1] : 0;
#pragma unroll
  for (int j = 0; j < 16; j++) {
    rs[base + j] = run; fill[base + j] = run; run += loc[j];
  }
  if (t == 1023) rs[N_NODES] = run;
}

// scatter + edge-MLP fused: assign sorted position, write srcs and both
// layers' h vectors directly at the sorted slot.
__global__ __launch_bounds__(256) void scatter_mlp_kernel(
    const int* __restrict__ ei, const float* __restrict__ ea,
    int* __restrict__ fill,
    const float* __restrict__ w1l1, const float* __restrict__ b1l1,
    const float* __restrict__ w2l1, const float* __restrict__ b2l1,
    int* __restrict__ srcs, f16* __restrict__ h1, f16* __restrict__ h2) {
  int e = blockIdx.x * blockDim.x + threadIdx.x;
  if (e >= N_EDGES) return;
  int pos = atomicAdd(&fill[ei[N_EDGES + e]], 1);
  srcs[pos] = ei[e];
  float a[EDGE_DIM];
#pragma unroll
  for (int d = 0; d < EDGE_DIM; d++) a[d] = ea[e * EDGE_DIM + d];
  f16 hv1[KH], hv2[KH];
#pragma unroll
  for (int k = 0; k < KH; k++) {
    float acc1 = b1l1[k], acc2 = b2l1[k];
#pragma unroll
    for (int d = 0; d < EDGE_DIM; d++) {
      acc1 += a[d] * w1l1[d * KH + k];
      acc2 += a[d] * w2l1[d * KH + k];
    }
    hv1[k] = (f16)fmaxf(acc1, 0.0f);
    hv2[k] = (f16)fmaxf(acc2, 0.0f);
  }
  f16x8* d1 = (f16x8*)(h1 + (size_t)pos * KH);
  f16x8* d2 = (f16x8*)(h2 + (size_t)pos * KH);
#pragma unroll
  for (int c = 0; c < 4; c++) {
    d1[c] = *(f16x8*)&hv1[c * 8];
    d2[c] = *(f16x8*)&hv2[c * 8];
  }
}

// 6 pack jobs (blockIdx.y): l2w -> Bp[i*128+o][k]; l2b/root -> K=128 slab layout
__global__ __launch_bounds__(256) void pack_all_kernel(
    const float* __restrict__ w1l2, const float* __restrict__ w2l2,
    const float* __restrict__ b1l2, const float* __restrict__ b2l2,
    const float* __restrict__ rt1, const float* __restrict__ rt2,
    f16* __restrict__ Bp1, f16* __restrict__ Bp2,
    f16* __restrict__ Rp1, f16* __restrict__ Rp2) {
  int y = blockIdx.y;
  int t = blockIdx.x * 256 + threadIdx.x;
  if (y < 2) {
    const float* l2w = y ? w2l2 : w1l2;
    f16* Bp = y ? Bp2 : Bp1;
    f16 tmp[KH];
#pragma unroll
    for (int k = 0; k < KH; k++) tmp[k] = (f16)l2w[(size_t)k * (D * D) + t];
    f16x8* dst = (f16x8*)(Bp + (size_t)t * KH);
#pragma unroll
    for (int c = 0; c < 4; c++) dst[c] = *(f16x8*)&tmp[c * 8];
  } else {
    const float* src = (y == 2) ? b1l2 : (y == 3) ? b2l2 : (y == 4) ? rt1 : rt2;
    f16* dst = (y == 2) ? (Bp1 + (size_t)D * D * KH)
             : (y == 3) ? (Bp2 + (size_t)D * D * KH)
             : (y == 4) ? Rp1 : Rp2;
    int i = t >> 7, o = t & 127;
    dst[((size_t)(i >> 5) * D + o) * KH + (i & 31)] = (f16)src[t];
  }
}

// msg GEMM, split-N: blockIdx.y picks 64-col half; mt=8, nt=1; register
// double-buffer pipeline over B i-slabs. Bias fold in the tail.
__global__ __launch_bounds__(256, 2) void msg_mfma_kernel(
    const float* __restrict__ xin, const f16* __restrict__ hf,
    const f16* __restrict__ Bp, const int* __restrict__ srcs,
    f16* __restrict__ msgf) {
  __shared__ f16 Xs[BM][XST];   // 34.8 KB
  __shared__ f16 Hs[BM][KH];    // 8 KB
  int t = threadIdx.x;
  int e0 = blockIdx.x * BM;

  ((f16x8*)Hs)[t] = ((const f16x8*)(hf + (size_t)e0 * KH))[t];
  ((f16x8*)Hs)[t + 256] = ((const f16x8*)(hf + (size_t)e0 * KH))[t + 256];
  {
    int r = t >> 1, q = t & 1;     // 2 threads per edge row
    int s = srcs[e0 + r];
    const float4* src = (const float4*)(xin + (size_t)s * D + q * 64);
    f16* dst = &Xs[r][q * 64];
#pragma unroll
    for (int c = 0; c < 16; c++) {
      float4 v = src[c];
      f16x4 h4 = {(f16)v.x, (f16)v.y, (f16)v.z, (f16)v.w};
      *(f16x4*)(dst + c * 4) = h4;
    }
  }

  int L = t & 63, w = t >> 6;
  int quad = L >> 4, lm = L & 15;
  int n0 = blockIdx.y * 64 + w * 16;

  const f16* bl = Bp + (size_t)(n0 + lm) * KH + quad * 8;
  const size_t istr = (size_t)D * KH;    // f16 stride per i

  f32x4 acc[8];
#pragma unroll
  for (int mt = 0; mt < 8; mt++) acc[mt] = (f32x4){0.f, 0.f, 0.f, 0.f};

  f16x8 bufA[8], bufB[8];

  auto loadg = [&](f16x8 (&buf)[8], int basei) {
#pragma unroll
    for (int jj = 0; jj < 8; jj++)
      buf[jj] = *(const f16x8*)(bl + (size_t)(basei + jj) * istr);
  };

  f16x8 hreg[8];

  auto compute = [&](f16x8 (&buf)[8], int ig) {
    f16x8 xv[8];
#pragma unroll
    for (int mt = 0; mt < 8; mt++)
      xv[mt] = *(const f16x8*)&Xs[mt * 16 + lm][ig];
#pragma unroll
    for (int jj = 0; jj < 8; jj++) {
#pragma unroll
      for (int mt = 0; mt < 8; mt++) {
        f16 xs = xv[mt][jj];
        f16x8 xb = {xs, xs, xs, xs, xs, xs, xs, xs};
        f16x8 a = hreg[mt] * xb;
        acc[mt] = __builtin_amdgcn_mfma_f32_16x16x32_f16(a, buf[jj], acc[mt], 0, 0, 0);
      }
    }
  };

  loadg(bufA, 0);                 // no LDS dependence: overlaps staging
  __syncthreads();

#pragma unroll
  for (int mt = 0; mt < 8; mt++)
    hreg[mt] = *(const f16x8*)&Hs[mt * 16 + lm][quad * 8];

#pragma unroll 1
  for (int g = 0; g < 8; g++) {
    loadg(bufB, 16 * g + 8);
    compute(bufA, 16 * g);
    loadg(bufA, 16 * g + 16);     // g=7: i=128..135 -> bias slabs + allocated slack
    compute(bufB, 16 * g + 8);
  }

  // l2b fold tail: K=128 GEMM, A = raw x fragments, B in bufA[0..3]
#pragma unroll
  for (int ig2 = 0; ig2 < 4; ig2++) {
#pragma unroll
    for (int mt = 0; mt < 8; mt++) {
      f16x8 a = *(const f16x8*)&Xs[mt * 16 + lm][ig2 * 32 + quad * 8];
      acc[mt] = __builtin_amdgcn_mfma_f32_16x16x32_f16(a, bufA[ig2], acc[mt], 0, 0, 0);
    }
  }

  // C/D: col = lane&15, row = quad*4 + reg
#pragma unroll
  for (int mt = 0; mt < 8; mt++)
#pragma unroll
    for (int r = 0; r < 4; r++)
      msgf[(size_t)(e0 + mt * 16 + quad * 4 + r) * D + n0 + lm] = (f16)acc[mt][r];
}

// node update: out = (relu?) bias + segmean(msgf) + x@root (f16 MFMA)
__global__ __launch_bounds__(256) void node_update_kernel(
    const float* __restrict__ xin, const f16* __restrict__ msgf,
    const int* __restrict__ rs, const f16* __restrict__ Rp,
    const float* __restrict__ bias, float* __restrict__ out, int do_relu) {
  __shared__ f16 Xs[NBL][XST];   // 8.7 KB
  __shared__ float Sls[NBL][D];  // 16.4 KB
  int t = threadIdx.x;
  int nb = blockIdx.x * NBL;

  {
    int r = t >> 3, q = t & 7;   // 8 threads per node row
    const float4* src = (const float4*)(xin + (size_t)(nb + r) * D + q * 16);
    f16* dst = &Xs[r][q * 16];
#pragma unroll
    for (int c = 0; c < 4; c++) {
      float4 v = src[c];
      f16x4 h4 = {(f16)v.x, (f16)v.y, (f16)v.z, (f16)v.w};
      *(f16x4*)(dst + c * 4) = h4;
    }
  }
  __syncthreads();

  // segment mean: 8 threads per node, 16 o's per thread, 16B vector msgf reads
  {
    int nl = t >> 3, o0 = (t & 7) * 16;
    int n = nb + nl;
    int a = rs[n], b = rs[n + 1];
    float sum[16];
#pragma unroll
    for (int j = 0; j < 16; j++) sum[j] = 0.f;
    for (int r = a; r < b; r++) {
      f16x8 v0 = *(const f16x8*)(msgf + (size_t)r * D + o0);
      f16x8 v1 = *(const f16x8*)(msgf + (size_t)r * D + o0 + 8);
#pragma unroll
      for (int j = 0; j < 8; j++) {
        sum[j] += (float)v0[j];
        sum[8 + j] += (float)v1[j];
      }
    }
    float inv = 1.0f / (float)max(b - a, 1);
#pragma unroll
    for (int j = 0; j < 16; j++) Sls[nl][o0 + j] = sum[j] * inv;
  }
  __syncthreads();

  // x@root via MFMA, K=128 (4 slabs), mt=2
  int L = t & 63, w = t >> 6;
  int quad = L >> 4, lm = L & 15;
  int n0 = w * 32;
  f32x4 acc[2][2];
#pragma unroll
  for (int mt = 0; mt < 2; mt++)
#pragma unroll
    for (int nt = 0; nt < 2; nt++)
      acc[mt][nt] = (f32x4){0.f, 0.f, 0.f, 0.f};
#pragma unroll
  for (int s4 = 0; s4 < 4; s4++) {
    const f16* b2l = Rp + ((size_t)s4 * D + n0 + lm) * KH + quad * 8;
    f16x8 b0 = *(const f16x8*)b2l;
    f16x8 b1 = *(const f16x8*)(b2l + 16 * KH);
#pragma unroll
    for (int mt = 0; mt < 2; mt++) {
      f16x8 a = *(const f16x8*)&Xs[mt * 16 + lm][s4 * 32 + quad * 8];
      acc[mt][0] = __builtin_amdgcn_mfma_f32_16x16x32_f16(a, b0, acc[mt][0], 0, 0, 0);
      acc[mt][1] = __builtin_amdgcn_mfma_f32_16x16x32_f16(a, b1, acc[mt][1], 0, 0, 0);
    }
  }
#pragma unroll
  for (int mt = 0; mt < 2; mt++)
#pragma unroll
    for (int r = 0; r < 4; r++) {
      Sls[mt * 16 + quad * 4 + r][n0 + lm] += acc[mt][0][r];
      Sls[mt * 16 + quad * 4 + r][n0 + 16 + lm] += acc[mt][1][r];
    }
  __syncthreads();

  {
    int o = t & 127, g = t >> 7;
    float bo = bias[o];
    for (int q = g * 16; q < g * 16 + 16; q++) {
      float v = bo + Sls[q][o];
      out[(size_t)(nb + q) * D + o] = do_relu ? fmaxf(v, 0.0f) : v;
    }
  }
}

extern "C" void kernel_launch(void* const* d_in, const int* in_sizes, int n_in,
                              void* d_out, int out_size, void* d_ws, size_t ws_size,
                              hipStream_t stream) {
  const float* x      = (const float*)d_in[0];
  const int*   ei     = (const int*)d_in[1];
  const float* ea     = (const float*)d_in[2];
  const float* w1_l1  = (const float*)d_in[3];
  const float* b1_l1  = (const float*)d_in[4];
  const float* w1_l2  = (const float*)d_in[5];
  const float* b1_l2  = (const float*)d_in[6];
  const float* w1_rt  = (const float*)d_in[7];
  const float* b1     = (const float*)d_in[8];
  const float* w2_l1  = (const float*)d_in[9];
  const float* b2_l1  = (const float*)d_in[10];
  const float* w2_l2  = (const float*)d_in[11];
  const float* b2_l2  = (const float*)d_in[12];
  const float* w2_rt  = (const float*)d_in[13];
  const float* b2     = (const float*)d_in[14];
  float* out = (float*)d_out;

  const size_t BPSZ = (size_t)D * D * KH + (size_t)D * D;
  f16* h1f = (f16*)d_ws;
  f16* h2f = h1f + (size_t)N_EDGES * KH;
  f16* Bp1 = h2f + (size_t)N_EDGES * KH;
  f16* Bp2 = Bp1 + BPSZ;
  f16* Rp1 = Bp2 + BPSZ;
  f16* Rp2 = Rp1 + (size_t)D * D;
  int* deg  = (int*)(Rp2 + (size_t)D * D);
  int* rs   = deg + N_NODES;
  int* fill = rs + N_NODES + 128;
  int* srcs = fill + N_NODES;
  f16* msgf = (f16*)(srcs + N_EDGES);

  hipMemsetAsync(deg, 0, N_NODES * sizeof(int), stream);
  deg_count_kernel<<<N_EDGES / 256, 256, 0, stream>>>(ei, deg);
  scan_kernel<<<1, 1024, 0, stream>>>(deg, rs, fill);
  scatter_mlp_kernel<<<N_EDGES / 256, 256, 0, stream>>>(
      ei, ea, fill, w1_l1, b1_l1, w2_l1, b2_l1, srcs, h1f, h2f);
  pack_all_kernel<<<dim3(D * D / 256, 6), 256, 0, stream>>>(
      w1_l2, w2_l2, b1_l2, b2_l2, w1_rt, w2_rt, Bp1, Bp2, Rp1, Rp2);

  // layer 1
  msg_mfma_kernel<<<dim3(N_EDGES / BM, 2), 256, 0, stream>>>(x, h1f, Bp1, srcs, msgf);
  node_update_kernel<<<N_NODES / NBL, 256, 0, stream>>>(x, msgf, rs, Rp1, b1, out, 1);
  // layer 2
  msg_mfma_kernel<<<dim3(N_EDGES / BM, 2), 256, 0, stream>>>(out, h2f, Bp2, srcs, msgf);
  node_update_kernel<<<N_NODES / NBL, 256, 0, stream>>>(out, msgf, rs, Rp2, b2, out, 1);
  // layer 3
  msg_mfma_kernel<<<dim3(N_EDGES / BM, 2), 256, 0, stream>>>(out, h2f, Bp2, srcs, msgf);
  node_update_kernel<<<N_NODES / NBL, 256, 0, stream>>>(out, msgf, rs, Rp2, b2, out, 0);
}

// Round 11
// 257.712 us; speedup vs baseline: 1.0732x; 1.0732x over previous
//
#include <hip/hip_runtime.h>

#define N_NODES 16384
#define N_EDGES 32768
#define D 128
#define EDGE_DIM 10
#define KH 32          // edge-hidden dim
#define BM 128         // edges per msg block
#define XST2 72        // msg Xs row stride (f16): 144B, 16B-aligned rows
#define XST 136        // node_update Xs pad (unchanged, proven)
#define NBL 32         // nodes per node_update block

typedef _Float16 f16;
typedef _Float16 f16x4 __attribute__((ext_vector_type(4)));
typedef _Float16 f16x8 __attribute__((ext_vector_type(8)));
typedef float f32x4 __attribute__((ext_vector_type(4)));

// ---- fused: deg count (y=0) + 6 pack jobs (y=1..6) ----
__global__ __launch_bounds__(256) void deg_pack_kernel(
    const int* __restrict__ ei, int* __restrict__ deg,
    const float* __restrict__ w1l2, const float* __restrict__ w2l2,
    const float* __restrict__ b1l2, const float* __restrict__ b2l2,
    const float* __restrict__ rt1, const float* __restrict__ rt2,
    f16* __restrict__ Bp1, f16* __restrict__ Bp2,
    f16* __restrict__ Rp1, f16* __restrict__ Rp2) {
  int y = blockIdx.y;
  if (y == 0) {
    int e = blockIdx.x * 256 + threadIdx.x;
    if (e < N_EDGES) atomicAdd(&deg[ei[N_EDGES + e]], 1);
    return;
  }
  if (blockIdx.x >= D * D / 256) return;
  int t = blockIdx.x * 256 + threadIdx.x;   // 0..16383
  int j = y - 1;
  if (j < 2) {
    const float* l2w = j ? w2l2 : w1l2;
    f16* Bp = j ? Bp2 : Bp1;
    f16 tmp[KH];
#pragma unroll
    for (int k = 0; k < KH; k++) tmp[k] = (f16)l2w[(size_t)k * (D * D) + t];
    f16x8* dst = (f16x8*)(Bp + (size_t)t * KH);
#pragma unroll
    for (int c = 0; c < 4; c++) dst[c] = *(f16x8*)&tmp[c * 8];
  } else {
    const float* src = (j == 2) ? b1l2 : (j == 3) ? b2l2 : (j == 4) ? rt1 : rt2;
    f16* dst = (j == 2) ? (Bp1 + (size_t)D * D * KH)
             : (j == 3) ? (Bp2 + (size_t)D * D * KH)
             : (j == 4) ? Rp1 : Rp2;
    int i = t >> 7, o = t & 127;
    dst[((size_t)(i >> 5) * D + o) * KH + (i & 31)] = (f16)src[t];
  }
}

__global__ __launch_bounds__(1024) void scan_kernel(
    const int* __restrict__ deg, int* __restrict__ rs, int* __restrict__ fill) {
  __shared__ int part[1024];
  int t = threadIdx.x;
  int base = t * 16;
  int loc[16], s = 0;
#pragma unroll
  for (int j = 0; j < 16; j++) { loc[j] = deg[base + j]; s += loc[j]; }
  part[t] = s;
  __syncthreads();
  for (int off = 1; off < 1024; off <<= 1) {
    int add = (t >= off) ? part[t - off] : 0;
    __syncthreads();
    part[t] += add;
    __syncthreads();
  }
  int run = t ? part[t - 1] : 0;
#pragma unroll
  for (int j = 0; j < 16; j++) {
    rs[base + j] = run; fill[base + j] = run; run += loc[j];
  }
  if (t == 1023) rs[N_NODES] = run;
}

// scatter + edge-MLP fused
__global__ __launch_bounds__(256) void scatter_mlp_kernel(
    const int* __restrict__ ei, const float* __restrict__ ea,
    int* __restrict__ fill,
    const float* __restrict__ w1l1, const float* __restrict__ b1l1,
    const float* __restrict__ w2l1, const float* __restrict__ b2l1,
    int* __restrict__ srcs, f16* __restrict__ h1, f16* __restrict__ h2) {
  int e = blockIdx.x * blockDim.x + threadIdx.x;
  if (e >= N_EDGES) return;
  int pos = atomicAdd(&fill[ei[N_EDGES + e]], 1);
  srcs[pos] = ei[e];
  float a[EDGE_DIM];
#pragma unroll
  for (int d = 0; d < EDGE_DIM; d++) a[d] = ea[e * EDGE_DIM + d];
  f16 hv1[KH], hv2[KH];
#pragma unroll
  for (int k = 0; k < KH; k++) {
    float acc1 = b1l1[k], acc2 = b2l1[k];
#pragma unroll
    for (int d = 0; d < EDGE_DIM; d++) {
      acc1 += a[d] * w1l1[d * KH + k];
      acc2 += a[d] * w2l1[d * KH + k];
    }
    hv1[k] = (f16)fmaxf(acc1, 0.0f);
    hv2[k] = (f16)fmaxf(acc2, 0.0f);
  }
  f16x8* d1 = (f16x8*)(h1 + (size_t)pos * KH);
  f16x8* d2 = (f16x8*)(h2 + (size_t)pos * KH);
#pragma unroll
  for (int c = 0; c < 4; c++) {
    d1[c] = *(f16x8*)&hv1[c * 8];
    d2[c] = *(f16x8*)&hv2[c * 8];
  }
}

// msg GEMM, split-K: blockIdx.y picks i-half [y*64, y*64+64). mt=8, nt=2,
// register double-buffer (4-i groups) over B. Partial rows -> msgfA/msgfB
// (f16, plain streaming stores); bias fold split by half (ig2 = 2y, 2y+1).
__global__ __launch_bounds__(256, 2) void msg_mfma_kernel(
    const float* __restrict__ xin, const f16* __restrict__ hf,
    const f16* __restrict__ Bp, const int* __restrict__ srcs,
    f16* __restrict__ msgfA, f16* __restrict__ msgfB) {
  __shared__ f16 Xs[BM][XST2];  // 18.4 KB (half of x cols)
  __shared__ f16 Hs[BM][KH];    // 8 KB
  int t = threadIdx.x;
  int e0 = blockIdx.x * BM;
  int y  = blockIdx.y;
  f16* msgf = y ? msgfB : msgfA;

  ((f16x8*)Hs)[t]       = ((const f16x8*)(hf + (size_t)e0 * KH))[t];
  ((f16x8*)Hs)[t + 256] = ((const f16x8*)(hf + (size_t)e0 * KH))[t + 256];
  {
    int r = t >> 1, q = t & 1;     // 2 threads per edge row, 32 f32 each
    int s = srcs[e0 + r];
    const float4* src = (const float4*)(xin + (size_t)s * D + y * 64 + q * 32);
    f16* dst = &Xs[r][q * 32];
#pragma unroll
    for (int c = 0; c < 8; c++) {
      float4 v = src[c];
      f16x4 h4 = {(f16)v.x, (f16)v.y, (f16)v.z, (f16)v.w};
      *(f16x4*)(dst + c * 4) = h4;
    }
  }

  int L = t & 63, w = t >> 6;
  int quad = L >> 4, lm = L & 15;
  int n0 = w * 32;

  const f16* bl = Bp + ((size_t)(y * 64) * D + n0 + lm) * KH + quad * 8;
  const size_t istr = (size_t)D * KH;    // f16 stride per i

  f32x4 acc[8][2];
#pragma unroll
  for (int mt = 0; mt < 8; mt++)
#pragma unroll
    for (int nt = 0; nt < 2; nt++)
      acc[mt][nt] = (f32x4){0.f, 0.f, 0.f, 0.f};

  f16x8 bufA[4][2], bufB[4][2];

  auto loadg = [&](f16x8 (&buf)[4][2], int basei) {
#pragma unroll
    for (int jj = 0; jj < 4; jj++) {
      const f16* bi = bl + (size_t)(basei + jj) * istr;
      buf[jj][0] = *(const f16x8*)bi;
      buf[jj][1] = *(const f16x8*)(bi + 16 * KH);
    }
  };

  f16x8 hreg[8];

  auto compute = [&](f16x8 (&buf)[4][2], int ig) {
    f16x4 xv[8];
#pragma unroll
    for (int mt = 0; mt < 8; mt++)
      xv[mt] = *(const f16x4*)&Xs[mt * 16 + lm][ig];
#pragma unroll
    for (int jj = 0; jj < 4; jj++) {
#pragma unroll
      for (int mt = 0; mt < 8; mt++) {
        f16 xs = xv[mt][jj];
        f16x8 xb = {xs, xs, xs, xs, xs, xs, xs, xs};
        f16x8 a = hreg[mt] * xb;
        acc[mt][0] = __builtin_amdgcn_mfma_f32_16x16x32_f16(a, buf[jj][0], acc[mt][0], 0, 0, 0);
        acc[mt][1] = __builtin_amdgcn_mfma_f32_16x16x32_f16(a, buf[jj][1], acc[mt][1], 0, 0, 0);
      }
    }
  };

  loadg(bufA, 0);                 // no LDS dependence: overlaps staging
  __syncthreads();

#pragma unroll
  for (int mt = 0; mt < 8; mt++)
    hreg[mt] = *(const f16x8*)&Hs[mt * 16 + lm][quad * 8];

#pragma unroll 1
  for (int g = 0; g < 8; g++) {
    loadg(bufB, 8 * g + 4);
    compute(bufA, 8 * g);
    loadg(bufA, 8 * g + 8);       // g=7 prefetches past range: allocated slack
    compute(bufB, 8 * g + 4);
  }

  // bias fold: this half handles ig2 = 2y, 2y+1 (uses only this half's x)
  {
    const f16* bb = Bp + (size_t)D * D * KH;
#pragma unroll
    for (int g2 = 0; g2 < 2; g2++) {
      int ig2 = 2 * y + g2;
      const f16* b2l = bb + ((size_t)ig2 * D + n0 + lm) * KH + quad * 8;
      f16x8 b0 = *(const f16x8*)b2l;
      f16x8 b1 = *(const f16x8*)(b2l + 16 * KH);
      int lc = g2 * 32 + quad * 8;
#pragma unroll
      for (int mt = 0; mt < 8; mt++) {
        f16x8 a = *(const f16x8*)&Xs[mt * 16 + lm][lc];
        acc[mt][0] = __builtin_amdgcn_mfma_f32_16x16x32_f16(a, b0, acc[mt][0], 0, 0, 0);
        acc[mt][1] = __builtin_amdgcn_mfma_f32_16x16x32_f16(a, b1, acc[mt][1], 0, 0, 0);
      }
    }
  }

  // C/D: col = lane&15 (+nt*16), row = quad*4 + reg
#pragma unroll
  for (int mt = 0; mt < 8; mt++)
#pragma unroll
    for (int r = 0; r < 4; r++) {
      f16* mg = msgf + (size_t)(e0 + mt * 16 + quad * 4 + r) * D + n0 + lm;
      mg[0]  = (f16)acc[mt][0][r];
      mg[16] = (f16)acc[mt][1][r];
    }
}

// node update: out = (relu?) bias + segmean(msgA+msgB) + x@root (f16 MFMA)
__global__ __launch_bounds__(256) void node_update_kernel(
    const float* __restrict__ xin, const f16* __restrict__ msgA,
    const f16* __restrict__ msgB, const int* __restrict__ rs,
    const f16* __restrict__ Rp, const float* __restrict__ bias,
    float* __restrict__ out, int do_relu) {
  __shared__ f16 Xs[NBL][XST];   // 8.7 KB
  __shared__ float Sls[NBL][D];  // 16.4 KB
  int t = threadIdx.x;
  int nb = blockIdx.x * NBL;

  {
    int r = t >> 3, q = t & 7;   // 8 threads per node row
    const float4* src = (const float4*)(xin + (size_t)(nb + r) * D + q * 16);
    f16* dst = &Xs[r][q * 16];
#pragma unroll
    for (int c = 0; c < 4; c++) {
      float4 v = src[c];
      f16x4 h4 = {(f16)v.x, (f16)v.y, (f16)v.z, (f16)v.w};
      *(f16x4*)(dst + c * 4) = h4;
    }
  }
  __syncthreads();

  // segment mean over contiguous sorted msg rows (both K-half partials)
  {
    int nl = t >> 3, o0 = (t & 7) * 16;
    int n = nb + nl;
    int a = rs[n], b = rs[n + 1];
    float sum[16];
#pragma unroll
    for (int j = 0; j < 16; j++) sum[j] = 0.f;
    for (int r = a; r < b; r++) {
      f16x8 a0 = *(const f16x8*)(msgA + (size_t)r * D + o0);
      f16x8 a1 = *(const f16x8*)(msgA + (size_t)r * D + o0 + 8);
      f16x8 b0 = *(const f16x8*)(msgB + (size_t)r * D + o0);
      f16x8 b1 = *(const f16x8*)(msgB + (size_t)r * D + o0 + 8);
#pragma unroll
      for (int j = 0; j < 8; j++) {
        sum[j]     += (float)a0[j] + (float)b0[j];
        sum[8 + j] += (float)a1[j] + (float)b1[j];
      }
    }
    float inv = 1.0f / (float)max(b - a, 1);
#pragma unroll
    for (int j = 0; j < 16; j++) Sls[nl][o0 + j] = sum[j] * inv;
  }
  __syncthreads();

  // x@root via MFMA, K=128 (4 slabs), mt=2
  int L = t & 63, w = t >> 6;
  int quad = L >> 4, lm = L & 15;
  int n0 = w * 32;
  f32x4 acc[2][2];
#pragma unroll
  for (int mt = 0; mt < 2; mt++)
#pragma unroll
    for (int nt = 0; nt < 2; nt++)
      acc[mt][nt] = (f32x4){0.f, 0.f, 0.f, 0.f};
#pragma unroll
  for (int s4 = 0; s4 < 4; s4++) {
    const f16* b2l = Rp + ((size_t)s4 * D + n0 + lm) * KH + quad * 8;
    f16x8 b0 = *(const f16x8*)b2l;
    f16x8 b1 = *(const f16x8*)(b2l + 16 * KH);
#pragma unroll
    for (int mt = 0; mt < 2; mt++) {
      f16x8 a = *(const f16x8*)&Xs[mt * 16 + lm][s4 * 32 + quad * 8];
      acc[mt][0] = __builtin_amdgcn_mfma_f32_16x16x32_f16(a, b0, acc[mt][0], 0, 0, 0);
      acc[mt][1] = __builtin_amdgcn_mfma_f32_16x16x32_f16(a, b1, acc[mt][1], 0, 0, 0);
    }
  }
#pragma unroll
  for (int mt = 0; mt < 2; mt++)
#pragma unroll
    for (int r = 0; r < 4; r++) {
      Sls[mt * 16 + quad * 4 + r][n0 + lm] += acc[mt][0][r];
      Sls[mt * 16 + quad * 4 + r][n0 + 16 + lm] += acc[mt][1][r];
    }
  __syncthreads();

  {
    int o = t & 127, g = t >> 7;
    float bo = bias[o];
    for (int q = g * 16; q < g * 16 + 16; q++) {
      float v = bo + Sls[q][o];
      out[(size_t)(nb + q) * D + o] = do_relu ? fmaxf(v, 0.0f) : v;
    }
  }
}

extern "C" void kernel_launch(void* const* d_in, const int* in_sizes, int n_in,
                              void* d_out, int out_size, void* d_ws, size_t ws_size,
                              hipStream_t stream) {
  const float* x      = (const float*)d_in[0];
  const int*   ei     = (const int*)d_in[1];
  const float* ea     = (const float*)d_in[2];
  const float* w1_l1  = (const float*)d_in[3];
  const float* b1_l1  = (const float*)d_in[4];
  const float* w1_l2  = (const float*)d_in[5];
  const float* b1_l2  = (const float*)d_in[6];
  const float* w1_rt  = (const float*)d_in[7];
  const float* b1     = (const float*)d_in[8];
  const float* w2_l1  = (const float*)d_in[9];
  const float* b2_l1  = (const float*)d_in[10];
  const float* w2_l2  = (const float*)d_in[11];
  const float* b2_l2  = (const float*)d_in[12];
  const float* w2_rt  = (const float*)d_in[13];
  const float* b2     = (const float*)d_in[14];
  float* out = (float*)d_out;

  const size_t BPSZ = (size_t)D * D * KH + (size_t)D * D + 32768;  // +slack for tail prefetch
  f16* h1f = (f16*)d_ws;
  f16* h2f = h1f + (size_t)N_EDGES * KH;
  f16* Bp1 = h2f + (size_t)N_EDGES * KH;
  f16* Bp2 = Bp1 + BPSZ;
  f16* Rp1 = Bp2 + BPSZ;
  f16* Rp2 = Rp1 + (size_t)D * D;
  int* deg  = (int*)(Rp2 + (size_t)D * D);
  int* rs   = deg + N_NODES;
  int* fill = rs + N_NODES + 128;
  int* srcs = fill + N_NODES;
  f16* msgA = (f16*)(srcs + N_EDGES);      // E*D f16 (8.4 MB)
  f16* msgB = msgA + (size_t)N_EDGES * D;  // E*D f16 (8.4 MB)

  hipMemsetAsync(deg, 0, N_NODES * sizeof(int), stream);
  deg_pack_kernel<<<dim3(N_EDGES / 256, 7), 256, 0, stream>>>(
      ei, deg, w1_l2, w2_l2, b1_l2, b2_l2, w1_rt, w2_rt, Bp1, Bp2, Rp1, Rp2);
  scan_kernel<<<1, 1024, 0, stream>>>(deg, rs, fill);
  scatter_mlp_kernel<<<N_EDGES / 256, 256, 0, stream>>>(
      ei, ea, fill, w1_l1, b1_l1, w2_l1, b2_l1, srcs, h1f, h2f);

  // layer 1
  msg_mfma_kernel<<<dim3(N_EDGES / BM, 2), 256, 0, stream>>>(x, h1f, Bp1, srcs, msgA, msgB);
  node_update_kernel<<<N_NODES / NBL, 256, 0, stream>>>(x, msgA, msgB, rs, Rp1, b1, out, 1);
  // layer 2
  msg_mfma_kernel<<<dim3(N_EDGES / BM, 2), 256, 0, stream>>>(out, h2f, Bp2, srcs, msgA, msgB);
  node_update_kernel<<<N_NODES / NBL, 256, 0, stream>>>(out, msgA, msgB, rs, Rp2, b2, out, 1);
  // layer 3
  msg_mfma_kernel<<<dim3(N_EDGES / BM, 2), 256, 0, stream>>>(out, h2f, Bp2, srcs, msgA, msgB);
  node_update_kernel<<<N_NODES / NBL, 256, 0, stream>>>(out, msgA, msgB, rs, Rp2, b2, out, 0);
}

// Round 12
// 236.031 us; speedup vs baseline: 1.1718x; 1.0919x over previous
//
#include <hip/hip_runtime.h>

#define N_NODES 16384
#define N_EDGES 32768
#define D 128
#define EDGE_DIM 10
#define KH 32          // edge-hidden dim
#define BM 128         // edges per msg block
#define XST2 72        // msg Xs row stride (f16): 144B, 16B-aligned rows
#define XST 136        // node_update Xs pad (unchanged, proven)
#define NBL 32         // nodes per node_update block

typedef _Float16 f16;
typedef _Float16 f16x4 __attribute__((ext_vector_type(4)));
typedef _Float16 f16x8 __attribute__((ext_vector_type(8)));
typedef float f32x4 __attribute__((ext_vector_type(4)));

// ---- fused: deg count (y=0) + 6 pack jobs (y=1..6) ----
__global__ __launch_bounds__(256) void deg_pack_kernel(
    const int* __restrict__ ei, int* __restrict__ deg,
    const float* __restrict__ w1l2, const float* __restrict__ w2l2,
    const float* __restrict__ b1l2, const float* __restrict__ b2l2,
    const float* __restrict__ rt1, const float* __restrict__ rt2,
    f16* __restrict__ Bp1, f16* __restrict__ Bp2,
    f16* __restrict__ Rp1, f16* __restrict__ Rp2) {
  int y = blockIdx.y;
  if (y == 0) {
    int e = blockIdx.x * 256 + threadIdx.x;
    if (e < N_EDGES) atomicAdd(&deg[ei[N_EDGES + e]], 1);
    return;
  }
  if (blockIdx.x >= D * D / 256) return;
  int t = blockIdx.x * 256 + threadIdx.x;   // 0..16383
  int j = y - 1;
  if (j < 2) {
    const float* l2w = j ? w2l2 : w1l2;
    f16* Bp = j ? Bp2 : Bp1;
    f16 tmp[KH];
#pragma unroll
    for (int k = 0; k < KH; k++) tmp[k] = (f16)l2w[(size_t)k * (D * D) + t];
    f16x8* dst = (f16x8*)(Bp + (size_t)t * KH);
#pragma unroll
    for (int c = 0; c < 4; c++) dst[c] = *(f16x8*)&tmp[c * 8];
  } else {
    const float* src = (j == 2) ? b1l2 : (j == 3) ? b2l2 : (j == 4) ? rt1 : rt2;
    f16* dst = (j == 2) ? (Bp1 + (size_t)D * D * KH)
             : (j == 3) ? (Bp2 + (size_t)D * D * KH)
             : (j == 4) ? Rp1 : Rp2;
    int i = t >> 7, o = t & 127;
    dst[((size_t)(i >> 5) * D + o) * KH + (i & 31)] = (f16)src[t];
  }
}

__global__ __launch_bounds__(1024) void scan_kernel(
    const int* __restrict__ deg, int* __restrict__ rs, int* __restrict__ fill) {
  __shared__ int part[1024];
  int t = threadIdx.x;
  int base = t * 16;
  int loc[16], s = 0;
#pragma unroll
  for (int j = 0; j < 16; j++) { loc[j] = deg[base + j]; s += loc[j]; }
  part[t] = s;
  __syncthreads();
  for (int off = 1; off < 1024; off <<= 1) {
    int add = (t >= off) ? part[t - off] : 0;
    __syncthreads();
    part[t] += add;
    __syncthreads();
  }
  int run = t ? part[t - 1] : 0;
#pragma unroll
  for (int j = 0; j < 16; j++) {
    rs[base + j] = run; fill[base + j] = run; run += loc[j];
  }
  if (t == 1023) rs[N_NODES] = run;
}

// light scatter: assign sorted position only (no heavy compute after atomic)
__global__ __launch_bounds__(256) void scatter_kernel(
    const int* __restrict__ ei, int* __restrict__ fill,
    int* __restrict__ perm, int* __restrict__ srcs) {
  int e = blockIdx.x * blockDim.x + threadIdx.x;
  if (e < N_EDGES) {
    int pos = atomicAdd(&fill[ei[N_EDGES + e]], 1);
    perm[pos] = e;
    srcs[pos] = ei[e];
  }
}

// edge MLP in dst-sorted order (gathered ea reads, coalesced h writes);
// blockIdx.y selects layer weights
__global__ __launch_bounds__(256) void edge_mlp_kernel(
    const float* __restrict__ ea, const int* __restrict__ perm,
    const float* __restrict__ w1l1, const float* __restrict__ b1l1,
    const float* __restrict__ w2l1, const float* __restrict__ b2l1,
    f16* __restrict__ h1, f16* __restrict__ h2) {
  int p = blockIdx.x * blockDim.x + threadIdx.x;
  const float* l1w = blockIdx.y ? w2l1 : w1l1;
  const float* l1b = blockIdx.y ? b2l1 : b1l1;
  f16* h = blockIdx.y ? h2 : h1;
  int e = perm[p];
  float a[EDGE_DIM];
#pragma unroll
  for (int d = 0; d < EDGE_DIM; d++) a[d] = ea[e * EDGE_DIM + d];
  f16 hv[KH];
#pragma unroll
  for (int k = 0; k < KH; k++) {
    float acc = l1b[k];
#pragma unroll
    for (int d = 0; d < EDGE_DIM; d++) acc += a[d] * l1w[d * KH + k];
    hv[k] = (f16)fmaxf(acc, 0.0f);
  }
  f16x8* dst = (f16x8*)(h + (size_t)p * KH);
#pragma unroll
  for (int c = 0; c < 4; c++) dst[c] = *(f16x8*)&hv[c * 8];
}

// msg GEMM, split-K: blockIdx.y picks i-half [y*64, y*64+64). mt=8, nt=2,
// register double-buffer (4-i groups) over B. Partial rows -> msgfA/msgfB
// (f16, plain streaming stores); bias fold split by half (ig2 = 2y, 2y+1).
__global__ __launch_bounds__(256, 2) void msg_mfma_kernel(
    const float* __restrict__ xin, const f16* __restrict__ hf,
    const f16* __restrict__ Bp, const int* __restrict__ srcs,
    f16* __restrict__ msgfA, f16* __restrict__ msgfB) {
  __shared__ f16 Xs[BM][XST2];  // 18.4 KB (half of x cols)
  __shared__ f16 Hs[BM][KH];    // 8 KB
  int t = threadIdx.x;
  int e0 = blockIdx.x * BM;
  int y  = blockIdx.y;
  f16* msgf = y ? msgfB : msgfA;

  ((f16x8*)Hs)[t]       = ((const f16x8*)(hf + (size_t)e0 * KH))[t];
  ((f16x8*)Hs)[t + 256] = ((const f16x8*)(hf + (size_t)e0 * KH))[t + 256];
  {
    int r = t >> 1, q = t & 1;     // 2 threads per edge row, 32 f32 each
    int s = srcs[e0 + r];
    const float4* src = (const float4*)(xin + (size_t)s * D + y * 64 + q * 32);
    f16* dst = &Xs[r][q * 32];
#pragma unroll
    for (int c = 0; c < 8; c++) {
      float4 v = src[c];
      f16x4 h4 = {(f16)v.x, (f16)v.y, (f16)v.z, (f16)v.w};
      *(f16x4*)(dst + c * 4) = h4;
    }
  }

  int L = t & 63, w = t >> 6;
  int quad = L >> 4, lm = L & 15;
  int n0 = w * 32;

  const f16* bl = Bp + ((size_t)(y * 64) * D + n0 + lm) * KH + quad * 8;
  const size_t istr = (size_t)D * KH;    // f16 stride per i

  f32x4 acc[8][2];
#pragma unroll
  for (int mt = 0; mt < 8; mt++)
#pragma unroll
    for (int nt = 0; nt < 2; nt++)
      acc[mt][nt] = (f32x4){0.f, 0.f, 0.f, 0.f};

  f16x8 bufA[4][2], bufB[4][2];

  auto loadg = [&](f16x8 (&buf)[4][2], int basei) {
#pragma unroll
    for (int jj = 0; jj < 4; jj++) {
      const f16* bi = bl + (size_t)(basei + jj) * istr;
      buf[jj][0] = *(const f16x8*)bi;
      buf[jj][1] = *(const f16x8*)(bi + 16 * KH);
    }
  };

  f16x8 hreg[8];

  auto compute = [&](f16x8 (&buf)[4][2], int ig) {
    f16x4 xv[8];
#pragma unroll
    for (int mt = 0; mt < 8; mt++)
      xv[mt] = *(const f16x4*)&Xs[mt * 16 + lm][ig];
#pragma unroll
    for (int jj = 0; jj < 4; jj++) {
#pragma unroll
      for (int mt = 0; mt < 8; mt++) {
        f16 xs = xv[mt][jj];
        f16x8 xb = {xs, xs, xs, xs, xs, xs, xs, xs};
        f16x8 a = hreg[mt] * xb;
        acc[mt][0] = __builtin_amdgcn_mfma_f32_16x16x32_f16(a, buf[jj][0], acc[mt][0], 0, 0, 0);
        acc[mt][1] = __builtin_amdgcn_mfma_f32_16x16x32_f16(a, buf[jj][1], acc[mt][1], 0, 0, 0);
      }
    }
  };

  loadg(bufA, 0);                 // no LDS dependence: overlaps staging
  __syncthreads();

#pragma unroll
  for (int mt = 0; mt < 8; mt++)
    hreg[mt] = *(const f16x8*)&Hs[mt * 16 + lm][quad * 8];

#pragma unroll 1
  for (int g = 0; g < 8; g++) {
    loadg(bufB, 8 * g + 4);
    compute(bufA, 8 * g);
    loadg(bufA, 8 * g + 8);       // g=7 prefetches past range: allocated slack
    compute(bufB, 8 * g + 4);
  }

  // bias fold: this half handles ig2 = 2y, 2y+1 (uses only this half's x)
  {
    const f16* bb = Bp + (size_t)D * D * KH;
#pragma unroll
    for (int g2 = 0; g2 < 2; g2++) {
      int ig2 = 2 * y + g2;
      const f16* b2l = bb + ((size_t)ig2 * D + n0 + lm) * KH + quad * 8;
      f16x8 b0 = *(const f16x8*)b2l;
      f16x8 b1 = *(const f16x8*)(b2l + 16 * KH);
      int lc = g2 * 32 + quad * 8;
#pragma unroll
      for (int mt = 0; mt < 8; mt++) {
        f16x8 a = *(const f16x8*)&Xs[mt * 16 + lm][lc];
        acc[mt][0] = __builtin_amdgcn_mfma_f32_16x16x32_f16(a, b0, acc[mt][0], 0, 0, 0);
        acc[mt][1] = __builtin_amdgcn_mfma_f32_16x16x32_f16(a, b1, acc[mt][1], 0, 0, 0);
      }
    }
  }

  // C/D: col = lane&15 (+nt*16), row = quad*4 + reg
#pragma unroll
  for (int mt = 0; mt < 8; mt++)
#pragma unroll
    for (int r = 0; r < 4; r++) {
      f16* mg = msgf + (size_t)(e0 + mt * 16 + quad * 4 + r) * D + n0 + lm;
      mg[0]  = (f16)acc[mt][0][r];
      mg[16] = (f16)acc[mt][1][r];
    }
}

// node update: out = (relu?) bias + segmean(msgA+msgB) + x@root (f16 MFMA)
__global__ __launch_bounds__(256) void node_update_kernel(
    const float* __restrict__ xin, const f16* __restrict__ msgA,
    const f16* __restrict__ msgB, const int* __restrict__ rs,
    const f16* __restrict__ Rp, const float* __restrict__ bias,
    float* __restrict__ out, int do_relu) {
  __shared__ f16 Xs[NBL][XST];   // 8.7 KB
  __shared__ float Sls[NBL][D];  // 16.4 KB
  int t = threadIdx.x;
  int nb = blockIdx.x * NBL;

  {
    int r = t >> 3, q = t & 7;   // 8 threads per node row
    const float4* src = (const float4*)(xin + (size_t)(nb + r) * D + q * 16);
    f16* dst = &Xs[r][q * 16];
#pragma unroll
    for (int c = 0; c < 4; c++) {
      float4 v = src[c];
      f16x4 h4 = {(f16)v.x, (f16)v.y, (f16)v.z, (f16)v.w};
      *(f16x4*)(dst + c * 4) = h4;
    }
  }
  __syncthreads();

  // segment mean over contiguous sorted msg rows (both K-half partials)
  {
    int nl = t >> 3, o0 = (t & 7) * 16;
    int n = nb + nl;
    int a = rs[n], b = rs[n + 1];
    float sum[16];
#pragma unroll
    for (int j = 0; j < 16; j++) sum[j] = 0.f;
    for (int r = a; r < b; r++) {
      f16x8 a0 = *(const f16x8*)(msgA + (size_t)r * D + o0);
      f16x8 a1 = *(const f16x8*)(msgA + (size_t)r * D + o0 + 8);
      f16x8 b0 = *(const f16x8*)(msgB + (size_t)r * D + o0);
      f16x8 b1 = *(const f16x8*)(msgB + (size_t)r * D + o0 + 8);
#pragma unroll
      for (int j = 0; j < 8; j++) {
        sum[j]     += (float)a0[j] + (float)b0[j];
        sum[8 + j] += (float)a1[j] + (float)b1[j];
      }
    }
    float inv = 1.0f / (float)max(b - a, 1);
#pragma unroll
    for (int j = 0; j < 16; j++) Sls[nl][o0 + j] = sum[j] * inv;
  }
  __syncthreads();

  // x@root via MFMA, K=128 (4 slabs), mt=2
  int L = t & 63, w = t >> 6;
  int quad = L >> 4, lm = L & 15;
  int n0 = w * 32;
  f32x4 acc[2][2];
#pragma unroll
  for (int mt = 0; mt < 2; mt++)
#pragma unroll
    for (int nt = 0; nt < 2; nt++)
      acc[mt][nt] = (f32x4){0.f, 0.f, 0.f, 0.f};
#pragma unroll
  for (int s4 = 0; s4 < 4; s4++) {
    const f16* b2l = Rp + ((size_t)s4 * D + n0 + lm) * KH + quad * 8;
    f16x8 b0 = *(const f16x8*)b2l;
    f16x8 b1 = *(const f16x8*)(b2l + 16 * KH);
#pragma unroll
    for (int mt = 0; mt < 2; mt++) {
      f16x8 a = *(const f16x8*)&Xs[mt * 16 + lm][s4 * 32 + quad * 8];
      acc[mt][0] = __builtin_amdgcn_mfma_f32_16x16x32_f16(a, b0, acc[mt][0], 0, 0, 0);
      acc[mt][1] = __builtin_amdgcn_mfma_f32_16x16x32_f16(a, b1, acc[mt][1], 0, 0, 0);
    }
  }
#pragma unroll
  for (int mt = 0; mt < 2; mt++)
#pragma unroll
    for (int r = 0; r < 4; r++) {
      Sls[mt * 16 + quad * 4 + r][n0 + lm] += acc[mt][0][r];
      Sls[mt * 16 + quad * 4 + r][n0 + 16 + lm] += acc[mt][1][r];
    }
  __syncthreads();

  {
    int o = t & 127, g = t >> 7;
    float bo = bias[o];
    for (int q = g * 16; q < g * 16 + 16; q++) {
      float v = bo + Sls[q][o];
      out[(size_t)(nb + q) * D + o] = do_relu ? fmaxf(v, 0.0f) : v;
    }
  }
}

extern "C" void kernel_launch(void* const* d_in, const int* in_sizes, int n_in,
                              void* d_out, int out_size, void* d_ws, size_t ws_size,
                              hipStream_t stream) {
  const float* x      = (const float*)d_in[0];
  const int*   ei     = (const int*)d_in[1];
  const float* ea     = (const float*)d_in[2];
  const float* w1_l1  = (const float*)d_in[3];
  const float* b1_l1  = (const float*)d_in[4];
  const float* w1_l2  = (const float*)d_in[5];
  const float* b1_l2  = (const float*)d_in[6];
  const float* w1_rt  = (const float*)d_in[7];
  const float* b1     = (const float*)d_in[8];
  const float* w2_l1  = (const float*)d_in[9];
  const float* b2_l1  = (const float*)d_in[10];
  const float* w2_l2  = (const float*)d_in[11];
  const float* b2_l2  = (const float*)d_in[12];
  const float* w2_rt  = (const float*)d_in[13];
  const float* b2     = (const float*)d_in[14];
  float* out = (float*)d_out;

  const size_t BPSZ = (size_t)D * D * KH + (size_t)D * D + 32768;  // +slack for tail prefetch
  f16* h1f = (f16*)d_ws;
  f16* h2f = h1f + (size_t)N_EDGES * KH;
  f16* Bp1 = h2f + (size_t)N_EDGES * KH;
  f16* Bp2 = Bp1 + BPSZ;
  f16* Rp1 = Bp2 + BPSZ;
  f16* Rp2 = Rp1 + (size_t)D * D;
  int* deg  = (int*)(Rp2 + (size_t)D * D);
  int* rs   = deg + N_NODES;
  int* fill = rs + N_NODES + 128;
  int* perm = fill + N_NODES;
  int* srcs = perm + N_EDGES;
  f16* msgA = (f16*)(srcs + N_EDGES);      // E*D f16 (8.4 MB)
  f16* msgB = msgA + (size_t)N_EDGES * D;  // E*D f16 (8.4 MB)

  hipMemsetAsync(deg, 0, N_NODES * sizeof(int), stream);
  deg_pack_kernel<<<dim3(N_EDGES / 256, 7), 256, 0, stream>>>(
      ei, deg, w1_l2, w2_l2, b1_l2, b2_l2, w1_rt, w2_rt, Bp1, Bp2, Rp1, Rp2);
  scan_kernel<<<1, 1024, 0, stream>>>(deg, rs, fill);
  scatter_kernel<<<N_EDGES / 256, 256, 0, stream>>>(ei, fill, perm, srcs);
  edge_mlp_kernel<<<dim3(N_EDGES / 256, 2), 256, 0, stream>>>(
      ea, perm, w1_l1, b1_l1, w2_l1, b2_l1, h1f, h2f);

  // layer 1
  msg_mfma_kernel<<<dim3(N_EDGES / BM, 2), 256, 0, stream>>>(x, h1f, Bp1, srcs, msgA, msgB);
  node_update_kernel<<<N_NODES / NBL, 256, 0, stream>>>(x, msgA, msgB, rs, Rp1, b1, out, 1);
  // layer 2
  msg_mfma_kernel<<<dim3(N_EDGES / BM, 2), 256, 0, stream>>>(out, h2f, Bp2, srcs, msgA, msgB);
  node_update_kernel<<<N_NODES / NBL, 256, 0, stream>>>(out, msgA, msgB, rs, Rp2, b2, out, 1);
  // layer 3
  msg_mfma_kernel<<<dim3(N_EDGES / BM, 2), 256, 0, stream>>>(out, h2f, Bp2, srcs, msgA, msgB);
  node_update_kernel<<<N_NODES / NBL, 256, 0, stream>>>(out, msgA, msgB, rs, Rp2, b2, out, 0);
}